// Round 15
// baseline (962.853 us; speedup 1.0000x reference)
//
#include <hip/hip_runtime.h>

typedef short short8 __attribute__((ext_vector_type(8)));
typedef float f32x4 __attribute__((ext_vector_type(4)));

#define XP_BYTES (16ull * 130 * 130 * 128 * 2)

static __device__ __forceinline__ unsigned short f2bf(float f) {
  unsigned u = __float_as_uint(f);
  u += 0x7FFFu + ((u >> 16) & 1u);
  return (unsigned short)(u >> 16);
}

static __device__ __forceinline__ void gload16(const void* g, void* l) {
  __builtin_amdgcn_global_load_lds(
      (const __attribute__((address_space(1))) void*)g,
      (__attribute__((address_space(3))) void*)l, 16, 0, 0);
}

// ---------------- weight rotation: (O*R,I,3,3) fp32 -> W2[n'=o*8+r][tap*128+ic] bf16
static __device__ __forceinline__ float wtap(const float* f, int yi, int xi) {
  bool valid = (yi >= 0) & (yi < 3) & (xi >= 0) & (xi < 3);
  int yc = min(max(yi, 0), 2), xc = min(max(xi, 0), 2);
  return valid ? f[yc * 3 + xc] : 0.f;
}

__global__ __launch_bounds__(256) void wprep_kernel(
    const float* __restrict__ w, const float* __restrict__ rot_alpha,
    unsigned short* __restrict__ w2) {
  int gid = blockIdx.x * 256 + threadIdx.x;  // 131072 = 1024 * 128
  int ic = gid & 127;
  int nr = gid >> 7;  // n' = o*8 + r
  int r = nr & 7;
  const float* wf = w + (size_t)nr * (128 * 9) + (size_t)ic * 9;
  float f[9];
#pragma unroll
  for (int q = 0; q < 9; ++q) f[q] = wf[q];
  float ang = rot_alpha[r] * 0.78539816339744830962f * (float)r;
  float sth, cth;
  sincosf(ang, &sth, &cth);
#pragma unroll
  for (int j = 0; j < 3; ++j) {
#pragma unroll
    for (int i = 0; i < 3; ++i) {
      float gy = (float)(j - 1), gx = (float)(i - 1);
      float xs = cth * gx - sth * gy;
      float ys = sth * gx + cth * gy;
      float ix = xs + 1.0f, iy = ys + 1.0f;
      float x0f = floorf(ix), y0f = floorf(iy);
      int x0 = (int)x0f, y0 = (int)y0f;
      float wx = ix - x0f, wy = iy - y0f;
      float acc = wtap(f, y0, x0) * (1.f - wy) * (1.f - wx)
                + wtap(f, y0, x0 + 1) * (1.f - wy) * wx
                + wtap(f, y0 + 1, x0) * wy * (1.f - wx)
                + wtap(f, y0 + 1, x0 + 1) * wy * wx;
      w2[(size_t)nr * 1152 + (size_t)(j * 3 + i) * 128 + ic] = f2bf(acc);
    }
  }
}

// ---------------- x: NCHW fp32 -> padded NHWC bf16 xp[16][130][130][128]
__global__ __launch_bounds__(256) void xprep_kernel(
    const float* __restrict__ x, unsigned short* __restrict__ xp) {
  const int yy = blockIdx.x;  // 0..129
  const int b = blockIdx.y;   // 0..15
  const int t = threadIdx.x;
  const size_t rowbase = ((size_t)b * 130 + yy) * (130 * 128);
  if (yy == 0 || yy == 129) {
    uint4 z = {0u, 0u, 0u, 0u};
    for (int i = t; i < 2080; i += 256)
      ((uint4*)(xp + rowbase))[i] = z;
    return;
  }
  const int y = yy - 1;
  __shared__ float lt[32][129];
  if (t < 32) {
    uint4 z = {0u, 0u, 0u, 0u};
    int xx = (t < 16) ? 0 : 129;
    int cc = (t & 15) * 8;
    *(uint4*)(xp + rowbase + (size_t)xx * 128 + cc) = z;
  }
  for (int c0 = 0; c0 < 128; c0 += 32) {
#pragma unroll
    for (int i = 0; i < 16; ++i) {
      int idx = i * 256 + t;
      int c = idx >> 7, wq = idx & 127;
      lt[c][wq] = x[(((size_t)b * 128 + c0 + c) * 128 + y) * 128 + wq];
    }
    __syncthreads();
#pragma unroll
    for (int i = 0; i < 2; ++i) {
      int u = i * 256 + t;
      int xx = u >> 2, cp = (u & 3) * 8;
      unsigned short v[8];
#pragma unroll
      for (int q = 0; q < 8; ++q) v[q] = f2bf(lt[cp + q][xx]);
      *(uint4*)(xp + rowbase + (size_t)(xx + 1) * 128 + c0 + cp) = *(uint4*)v;
    }
    __syncthreads();
  }
}

// ---------------- implicit-GEMM conv, 128x128 tile, BK=32, 4 waves.
// WAVE-PRIVATE pipelines: each wave owns 16 KiB LDS (A 64x32 + B 64x32,
// double-buffered) and stages its own panels — NO s_barrier in the K-loop;
// sync is per-wave vmcnt(8) only (counts own loads; regions disjoint).
// Kills the lockstep convoy stall. 2 blocks/CU, 64 KiB LDS/block.
// LDS: [2 buf][4 wave][A 2048 | B 2048] shorts.
__global__ __launch_bounds__(256, 2) void conv_kernel(
    const unsigned short* __restrict__ xp,
    const unsigned short* __restrict__ w2,
    float* __restrict__ out) {
  __shared__ unsigned short lds[32768];  // 64 KiB

  const int tid = threadIdx.x;
  const int lane = tid & 63;
  const int wv = tid >> 6;  // 0..3
  const int wr = wv >> 1;   // M half (64 rows)
  const int wc = wv & 1;    // N half (64 n')

  const int bid = blockIdx.x;
  const int wg = (bid & 7) * 2048 + (bid >> 3);  // XCD swizzle (16384 % 8 == 0)
  const int mblk = wg >> 3;  // 0..2047
  const int nblk = wg & 7;   // 0..7
  const int b = mblk >> 7;
  const int y = mblk & 127;

  // per-wave staging decode: lane covers panel row (lane>>2), slot (lane&3)
  const int gsl = (lane & 3) ^ ((lane >> 3) & 3);  // inverse-swizzled k-group
  const unsigned short* xw =
      xp + ((size_t)(b * 130 + y)) * 130 * 128 +
      (size_t)(wr * 64 + (lane >> 2)) * 128 + gsl * 8;
  const unsigned short* wB =
      w2 + (size_t)(nblk * 128 + wc * 64 + (lane >> 2)) * 1152 + gsl * 8;

  const int l15 = lane & 15;
  const int lhi = lane >> 4;
  const int aRd = l15 * 32 + ((lhi ^ ((l15 >> 1) & 3)) * 8);  // within panel
  unsigned short* const myl = lds + wv * 4096;  // + P*16384; B at +2048

  f32x4 acc[4][4];
#pragma unroll
  for (int mf = 0; mf < 4; ++mf)
#pragma unroll
    for (int nf = 0; nf < 4; ++nf) acc[mf][nf] = (f32x4){0.f, 0.f, 0.f, 0.f};

  // stage K-tile T (tap=T>>2, cq=T&3) into buf P: 8 per-wave gloads
#define STAGE_T(P, T)                                                         \
  {                                                                           \
    const int tp_ = (T) >> 2, cq_ = (T) & 3;                                  \
    const int dy_ = tp_ / 3, dx_ = tp_ - dy_ * 3;                             \
    const unsigned short* sa_ = xw + (size_t)(dy_ * 130 + dx_) * 128 + cq_ * 32; \
    const unsigned short* sb_ = wB + tp_ * 128 + cq_ * 32;                    \
    _Pragma("unroll") for (int i_ = 0; i_ < 4; ++i_)                          \
        gload16(sa_ + (size_t)i_ * 16 * 128, myl + (P) * 16384 + i_ * 512);   \
    _Pragma("unroll") for (int i_ = 0; i_ < 4; ++i_)                          \
        gload16(sb_ + (size_t)i_ * 16 * 1152,                                 \
                myl + (P) * 16384 + 2048 + i_ * 512);                         \
  }

#define VMW8 asm volatile("s_waitcnt vmcnt(8)" ::: "memory")
#define VMW0 asm volatile("s_waitcnt vmcnt(0)" ::: "memory")
#define SCH0 __builtin_amdgcn_sched_barrier(0)

  // tile T from buf P; stage T+1 into P^1; wave-local, no barrier
#define BODY(P, T)                                                            \
  {                                                                           \
    SCH0;                                                                     \
    if ((T) + 1 < 36) { STAGE_T((P) ^ 1, (T) + 1); VMW8; }                    \
    else { VMW0; }                                                            \
    SCH0;                                                                     \
    const unsigned short* pA_ = myl + (P) * 16384 + aRd;                      \
    const unsigned short* pB_ = myl + (P) * 16384 + 2048 + aRd;               \
    short8 af[4], bf[4];                                                      \
    _Pragma("unroll") for (int q = 0; q < 4; ++q)                             \
        af[q] = *(const short8*)(pA_ + q * 512);                              \
    _Pragma("unroll") for (int n = 0; n < 4; ++n)                             \
        bf[n] = *(const short8*)(pB_ + n * 512);                              \
    __builtin_amdgcn_s_setprio(1);                                            \
    _Pragma("unroll") for (int q = 0; q < 4; ++q)                             \
        _Pragma("unroll") for (int n = 0; n < 4; ++n)                         \
            acc[q][n] = __builtin_amdgcn_mfma_f32_16x16x32_bf16(              \
                af[q], bf[n], acc[q][n], 0, 0, 0);                            \
    __builtin_amdgcn_s_setprio(0);                                            \
  }

  // ---- prologue: stage t0 -> buf0 (8 loads; the loop's first wait handles it)
  STAGE_T(0, 0);

#pragma unroll 1
  for (int j = 0; j < 18; ++j) {
    BODY(0, 2 * j);
    BODY(1, 2 * j + 1);
  }

#undef BODY
#undef STAGE_T
#undef VMW8
#undef VMW0
#undef SCH0

  // ---- epilogue: max over 8 rotations (8 adjacent n' cols), coalesced store
  __syncthreads();  // all waves done with private LDS before lE reuse
  float* lE = (float*)lds;  // [128 pix][17] fp32
#pragma unroll
  for (int mf = 0; mf < 4; ++mf)
#pragma unroll
    for (int nf = 0; nf < 4; ++nf)
#pragma unroll
      for (int j = 0; j < 4; ++j) {
        float v = acc[mf][nf][j];
        v = fmaxf(v, __shfl_xor(v, 1, 64));
        v = fmaxf(v, __shfl_xor(v, 2, 64));
        v = fmaxf(v, __shfl_xor(v, 4, 64));
        if ((lane & 7) == 0) {
          int pix = wr * 64 + mf * 16 + lhi * 4 + j;
          int ol = wc * 8 + nf * 2 + ((lane >> 3) & 1);
          lE[pix * 17 + ol] = v;
        }
      }
  __syncthreads();
  const size_t obase = ((size_t)(b * 128 + nblk * 16) * 128 + y) * 128;
#pragma unroll
  for (int i = 0; i < 8; ++i) {
    int idx = i * 256 + tid;
    int ol = idx >> 7;   // 0..15
    int xx = idx & 127;
    out[obase + (size_t)ol * 16384 + xx] = lE[xx * 17 + ol];
  }
}

extern "C" void kernel_launch(void* const* d_in, const int* in_sizes, int n_in,
                              void* d_out, int out_size, void* d_ws, size_t ws_size,
                              hipStream_t stream) {
  const float* x = (const float*)d_in[0];
  const float* w = (const float*)d_in[1];
  const float* ra = (const float*)d_in[2];
  float* out = (float*)d_out;
  unsigned short* xp = (unsigned short*)d_ws;
  unsigned short* w2 = (unsigned short*)((char*)d_ws + XP_BYTES);

  hipLaunchKernelGGL(wprep_kernel, dim3(512), dim3(256), 0, stream, w, ra, w2);
  hipLaunchKernelGGL(xprep_kernel, dim3(130, 16), dim3(256), 0, stream, x, xp);
  hipLaunchKernelGGL(conv_kernel, dim3(16384), dim3(256), 0, stream, xp, w2, out);
}

// Round 16
// 732.726 us; speedup vs baseline: 1.3141x; 1.3141x over previous
//
#include <hip/hip_runtime.h>

typedef short short8 __attribute__((ext_vector_type(8)));
typedef float f32x4 __attribute__((ext_vector_type(4)));

#define XP_BYTES (16ull * 130 * 130 * 128 * 2)

static __device__ __forceinline__ unsigned short f2bf(float f) {
  unsigned u = __float_as_uint(f);
  u += 0x7FFFu + ((u >> 16) & 1u);
  return (unsigned short)(u >> 16);
}

static __device__ __forceinline__ void gload16(const void* g, void* l) {
  __builtin_amdgcn_global_load_lds(
      (const __attribute__((address_space(1))) void*)g,
      (__attribute__((address_space(3))) void*)l, 16, 0, 0);
}

// ---------------- weight rotation: (O*R,I,3,3) fp32 -> W2[n'=o*8+r][tap*128+ic] bf16
static __device__ __forceinline__ float wtap(const float* f, int yi, int xi) {
  bool valid = (yi >= 0) & (yi < 3) & (xi >= 0) & (xi < 3);
  int yc = min(max(yi, 0), 2), xc = min(max(xi, 0), 2);
  return valid ? f[yc * 3 + xc] : 0.f;
}

__global__ __launch_bounds__(256) void wprep_kernel(
    const float* __restrict__ w, const float* __restrict__ rot_alpha,
    unsigned short* __restrict__ w2) {
  int gid = blockIdx.x * 256 + threadIdx.x;  // 131072 = 1024 * 128
  int ic = gid & 127;
  int nr = gid >> 7;  // n' = o*8 + r
  int r = nr & 7;
  const float* wf = w + (size_t)nr * (128 * 9) + (size_t)ic * 9;
  float f[9];
#pragma unroll
  for (int q = 0; q < 9; ++q) f[q] = wf[q];
  float ang = rot_alpha[r] * 0.78539816339744830962f * (float)r;
  float sth, cth;
  sincosf(ang, &sth, &cth);
#pragma unroll
  for (int j = 0; j < 3; ++j) {
#pragma unroll
    for (int i = 0; i < 3; ++i) {
      float gy = (float)(j - 1), gx = (float)(i - 1);
      float xs = cth * gx - sth * gy;
      float ys = sth * gx + cth * gy;
      float ix = xs + 1.0f, iy = ys + 1.0f;
      float x0f = floorf(ix), y0f = floorf(iy);
      int x0 = (int)x0f, y0 = (int)y0f;
      float wx = ix - x0f, wy = iy - y0f;
      float acc = wtap(f, y0, x0) * (1.f - wy) * (1.f - wx)
                + wtap(f, y0, x0 + 1) * (1.f - wy) * wx
                + wtap(f, y0 + 1, x0) * wy * (1.f - wx)
                + wtap(f, y0 + 1, x0 + 1) * wy * wx;
      w2[(size_t)nr * 1152 + (size_t)(j * 3 + i) * 128 + ic] = f2bf(acc);
    }
  }
}

// ---------------- x: NCHW fp32 -> padded NHWC bf16 xp[16][130][130][128]
__global__ __launch_bounds__(256) void xprep_kernel(
    const float* __restrict__ x, unsigned short* __restrict__ xp) {
  const int yy = blockIdx.x;  // 0..129
  const int b = blockIdx.y;   // 0..15
  const int t = threadIdx.x;
  const size_t rowbase = ((size_t)b * 130 + yy) * (130 * 128);
  if (yy == 0 || yy == 129) {
    uint4 z = {0u, 0u, 0u, 0u};
    for (int i = t; i < 2080; i += 256)
      ((uint4*)(xp + rowbase))[i] = z;
    return;
  }
  const int y = yy - 1;
  __shared__ float lt[32][129];
  if (t < 32) {
    uint4 z = {0u, 0u, 0u, 0u};
    int xx = (t < 16) ? 0 : 129;
    int cc = (t & 15) * 8;
    *(uint4*)(xp + rowbase + (size_t)xx * 128 + cc) = z;
  }
  for (int c0 = 0; c0 < 128; c0 += 32) {
#pragma unroll
    for (int i = 0; i < 16; ++i) {
      int idx = i * 256 + t;
      int c = idx >> 7, wq = idx & 127;
      lt[c][wq] = x[(((size_t)b * 128 + c0 + c) * 128 + y) * 128 + wq];
    }
    __syncthreads();
#pragma unroll
    for (int i = 0; i < 2; ++i) {
      int u = i * 256 + t;
      int xx = u >> 2, cp = (u & 3) * 8;
      unsigned short v[8];
#pragma unroll
      for (int q = 0; q < 8; ++q) v[q] = f2bf(lt[cp + q][xx]);
      *(uint4*)(xp + rowbase + (size_t)(xx + 1) * 128 + c0 + cp) = *(uint4*)v;
    }
    __syncthreads();
  }
}

// ---------------- implicit-GEMM conv, 128x128 tile, BK=32, 4 waves, 32 KiB LDS,
// double-buffered, 4 blocks/CU (R11 champion) + static-offset K-loop:
// outer jj = dy (3 runtime iters), inner 12 fully-unrolled static tiles
// (dx = i>>2, cq = i&3 compile-time) — no div-by-3, offsets constant-folded.
// Frag reads interleaved af0,bf0,af1,bf1,... (first MFMA operands land first).
// LDS: A[2 buf][128 row][32 k] @ 0 + B[2 buf][128 n'][32 k] @ 8192 shorts.
__global__ __launch_bounds__(256, 4) void conv_kernel(
    const unsigned short* __restrict__ xp,
    const unsigned short* __restrict__ w2,
    float* __restrict__ out) {
  __shared__ unsigned short lds[16384];  // 32 KiB

  const int tid = threadIdx.x;
  const int lane = tid & 63;
  const int wv = tid >> 6;  // 0..3
  const int wr = wv >> 1;   // M half (64 rows)
  const int wc = wv & 1;    // N half (64 n')

  const int bid = blockIdx.x;
  const int wg = (bid & 7) * 2048 + (bid >> 3);  // XCD swizzle (16384 % 8 == 0)
  const int mblk = wg >> 3;  // 0..2047
  const int nblk = wg & 7;   // 0..7
  const int b = mblk >> 7;
  const int y = mblk & 127;

  // staging decode: thread t covers row r0 (0..63), lds slot s0 (16B, 4/row)
  const int r0 = tid >> 2;
  const int s0 = tid & 3;
  const int g0 = s0 ^ ((r0 >> 1) & 3);  // inverse swizzle on global source

  const unsigned short* xpt =
      xp + (size_t)(b * 130 + y) * 130 * 128 + r0 * 128 + g0 * 8;
  const unsigned short* wpt =
      w2 + (size_t)nblk * 128 * 1152 + (size_t)r0 * 1152 + g0 * 8;

  const int l15 = lane & 15;
  const int lhi = lane >> 4;
  const int sa = (lhi ^ ((l15 >> 1) & 3)) * 8;  // read-side swizzled slot
  const int aRd = wr * 2048 + l15 * 32 + sa;           // + P*4096
  const int bRd = 8192 + wc * 2048 + l15 * 32 + sa;    // + P*4096

  f32x4 acc[4][4];
#pragma unroll
  for (int mf = 0; mf < 4; ++mf)
#pragma unroll
    for (int nf = 0; nf < 4; ++nf) acc[mf][nf] = (f32x4){0.f, 0.f, 0.f, 0.f};

  // stage tile (dx DX, cq CQ) from bases XB/WB into buf P: 4 gloads
  // A: ((hf*64+DX)*128 + CQ*32) off XB ; B: (hf*73728 + DX*128 + CQ*32) off WB
#define STAGE_I(P, XB, WB, DX, CQ)                                            \
  {                                                                           \
    gload16((XB) + (DX) * 128 + (CQ) * 32, lds + (P) * 4096 + wv * 512);      \
    gload16((XB) + (64 + (DX)) * 128 + (CQ) * 32,                             \
            lds + (P) * 4096 + 2048 + wv * 512);                              \
    gload16((WB) + (DX) * 128 + (CQ) * 32,                                    \
            lds + 8192 + (P) * 4096 + wv * 512);                              \
    gload16((WB) + 73728 + (DX) * 128 + (CQ) * 32,                            \
            lds + 8192 + (P) * 4096 + 2048 + wv * 512);                       \
  }

#define VMW0 asm volatile("s_waitcnt vmcnt(0)" ::: "memory")
#define SCH0 __builtin_amdgcn_sched_barrier(0)

  // ---- prologue: stage tile (jj=0,i=0) -> buf0; force it; barrier
  STAGE_I(0, xpt, wpt, 0, 0);
  VMW0;
  SCH0;
  __builtin_amdgcn_s_barrier();

#pragma unroll 1
  for (int jj = 0; jj < 3; ++jj) {  // jj == dy
    const unsigned short* XB = xpt + jj * 16640;  // dy*130*128 shorts
    const unsigned short* WB = wpt + jj * 384;    // dy*3*128 shorts
    const bool lastj = (jj == 2);
#pragma unroll
    for (int i = 0; i < 12; ++i) {  // dx = i>>2, cq = i&3 (compile-time)
      const int P = i & 1;
      if (i < 11) {
        STAGE_I(P ^ 1, XB, WB, (i + 1) >> 2, (i + 1) & 3);
      } else if (!lastj) {
        STAGE_I(P ^ 1, XB + 16640, WB + 384, 0, 0);
      }
      const unsigned short* pA_ = lds + P * 4096 + aRd;
      const unsigned short* pB_ = lds + P * 4096 + bRd;
      short8 af[4], bf[4];
#pragma unroll
      for (int q = 0; q < 4; ++q) {  // interleaved: af0,bf0,af1,bf1,...
        af[q] = *(const short8*)(pA_ + q * 512);
        bf[q] = *(const short8*)(pB_ + q * 512);
      }
      __builtin_amdgcn_s_setprio(1);
#pragma unroll
      for (int q = 0; q < 4; ++q)
#pragma unroll
        for (int n = 0; n < 4; ++n)
          acc[q][n] = __builtin_amdgcn_mfma_f32_16x16x32_bf16(
              af[q], bf[n], acc[q][n], 0, 0, 0);
      __builtin_amdgcn_s_setprio(0);
      SCH0;
      VMW0;
      __builtin_amdgcn_s_barrier();
    }
  }

#undef STAGE_I
#undef VMW0
#undef SCH0

  // ---- epilogue: max over 8 rotations (8 adjacent n' cols), coalesced store
  float* lE = (float*)lds;  // [128 pix][17] fp32
#pragma unroll
  for (int mf = 0; mf < 4; ++mf)
#pragma unroll
    for (int nf = 0; nf < 4; ++nf)
#pragma unroll
      for (int j = 0; j < 4; ++j) {
        float v = acc[mf][nf][j];
        v = fmaxf(v, __shfl_xor(v, 1, 64));
        v = fmaxf(v, __shfl_xor(v, 2, 64));
        v = fmaxf(v, __shfl_xor(v, 4, 64));
        if ((lane & 7) == 0) {
          int pix = wr * 64 + mf * 16 + lhi * 4 + j;
          int ol = wc * 8 + nf * 2 + ((lane >> 3) & 1);
          lE[pix * 17 + ol] = v;
        }
      }
  __syncthreads();
  const size_t obase = ((size_t)(b * 128 + nblk * 16) * 128 + y) * 128;
#pragma unroll
  for (int i = 0; i < 8; ++i) {
    int idx = i * 256 + tid;
    int ol = idx >> 7;   // 0..15
    int xx = idx & 127;
    out[obase + (size_t)ol * 16384 + xx] = lE[xx * 17 + ol];
  }
}

extern "C" void kernel_launch(void* const* d_in, const int* in_sizes, int n_in,
                              void* d_out, int out_size, void* d_ws, size_t ws_size,
                              hipStream_t stream) {
  const float* x = (const float*)d_in[0];
  const float* w = (const float*)d_in[1];
  const float* ra = (const float*)d_in[2];
  float* out = (float*)d_out;
  unsigned short* xp = (unsigned short*)d_ws;
  unsigned short* w2 = (unsigned short*)((char*)d_ws + XP_BYTES);

  hipLaunchKernelGGL(wprep_kernel, dim3(512), dim3(256), 0, stream, w, ra, w2);
  hipLaunchKernelGGL(xprep_kernel, dim3(130, 16), dim3(256), 0, stream, x, xp);
  hipLaunchKernelGGL(conv_kernel, dim3(16384), dim3(256), 0, stream, xp, w2, out);
}

// Round 18
// 722.425 us; speedup vs baseline: 1.3328x; 1.0143x over previous
//
#include <hip/hip_runtime.h>

typedef short short8 __attribute__((ext_vector_type(8)));
typedef float f32x4 __attribute__((ext_vector_type(4)));

#define XP_BYTES (16ull * 130 * 130 * 128 * 2)

static __device__ __forceinline__ unsigned short f2bf(float f) {
  unsigned u = __float_as_uint(f);
  u += 0x7FFFu + ((u >> 16) & 1u);
  return (unsigned short)(u >> 16);
}

static __device__ __forceinline__ void gload16(const void* g, void* l) {
  __builtin_amdgcn_global_load_lds(
      (const __attribute__((address_space(1))) void*)g,
      (__attribute__((address_space(3))) void*)l, 16, 0, 0);
}

// ---------------- weight rotation: (O*R,I,3,3) fp32 -> W2[n'=o*8+r][tap*128+ic] bf16
static __device__ __forceinline__ float wtap(const float* f, int yi, int xi) {
  bool valid = (yi >= 0) & (yi < 3) & (xi >= 0) & (xi < 3);
  int yc = min(max(yi, 0), 2), xc = min(max(xi, 0), 2);
  return valid ? f[yc * 3 + xc] : 0.f;
}

__global__ __launch_bounds__(256) void wprep_kernel(
    const float* __restrict__ w, const float* __restrict__ rot_alpha,
    unsigned short* __restrict__ w2) {
  int gid = blockIdx.x * 256 + threadIdx.x;  // 131072 = 1024 * 128
  int ic = gid & 127;
  int nr = gid >> 7;  // n' = o*8 + r
  int r = nr & 7;
  const float* wf = w + (size_t)nr * (128 * 9) + (size_t)ic * 9;
  float f[9];
#pragma unroll
  for (int q = 0; q < 9; ++q) f[q] = wf[q];
  float ang = rot_alpha[r] * 0.78539816339744830962f * (float)r;
  float sth, cth;
  sincosf(ang, &sth, &cth);
#pragma unroll
  for (int j = 0; j < 3; ++j) {
#pragma unroll
    for (int i = 0; i < 3; ++i) {
      float gy = (float)(j - 1), gx = (float)(i - 1);
      float xs = cth * gx - sth * gy;
      float ys = sth * gx + cth * gy;
      float ix = xs + 1.0f, iy = ys + 1.0f;
      float x0f = floorf(ix), y0f = floorf(iy);
      int x0 = (int)x0f, y0 = (int)y0f;
      float wx = ix - x0f, wy = iy - y0f;
      float acc = wtap(f, y0, x0) * (1.f - wy) * (1.f - wx)
                + wtap(f, y0, x0 + 1) * (1.f - wy) * wx
                + wtap(f, y0 + 1, x0) * wy * (1.f - wx)
                + wtap(f, y0 + 1, x0 + 1) * wy * wx;
      w2[(size_t)nr * 1152 + (size_t)(j * 3 + i) * 128 + ic] = f2bf(acc);
    }
  }
}

// ---------------- x: NCHW fp32 -> padded NHWC bf16 xp[16][130][130][128]
__global__ __launch_bounds__(256) void xprep_kernel(
    const float* __restrict__ x, unsigned short* __restrict__ xp) {
  const int yy = blockIdx.x;  // 0..129
  const int b = blockIdx.y;   // 0..15
  const int t = threadIdx.x;
  const size_t rowbase = ((size_t)b * 130 + yy) * (130 * 128);
  if (yy == 0 || yy == 129) {
    uint4 z = {0u, 0u, 0u, 0u};
    for (int i = t; i < 2080; i += 256)
      ((uint4*)(xp + rowbase))[i] = z;
    return;
  }
  const int y = yy - 1;
  __shared__ float lt[32][129];
  if (t < 32) {
    uint4 z = {0u, 0u, 0u, 0u};
    int xx = (t < 16) ? 0 : 129;
    int cc = (t & 15) * 8;
    *(uint4*)(xp + rowbase + (size_t)xx * 128 + cc) = z;
  }
  for (int c0 = 0; c0 < 128; c0 += 32) {
#pragma unroll
    for (int i = 0; i < 16; ++i) {
      int idx = i * 256 + t;
      int c = idx >> 7, wq = idx & 127;
      lt[c][wq] = x[(((size_t)b * 128 + c0 + c) * 128 + y) * 128 + wq];
    }
    __syncthreads();
#pragma unroll
    for (int i = 0; i < 2; ++i) {
      int u = i * 256 + t;
      int xx = u >> 2, cp = (u & 3) * 8;
      unsigned short v[8];
#pragma unroll
      for (int q = 0; q < 8; ++q) v[q] = f2bf(lt[cp + q][xx]);
      *(uint4*)(xp + rowbase + (size_t)(xx + 1) * 128 + c0 + cp) = *(uint4*)v;
    }
    __syncthreads();
  }
}

// ---------------- implicit-GEMM conv, 128x128 tile, BK=32, 4 waves, 48 KiB LDS,
// TRIPLE-buffered -> 3 independent blocks per CU (12 waves/CU) for TLP latency
// hiding. Per K-tile: stage t+2 into buf (t+2)%3 (4 gloads); 8 ds_read_b128;
// 16 MFMA; vmcnt(4) forces t+1 landed (8 outstanding: t+1 x4 + t+2 x4 -> allow
// only newest 4). Loop unrolled x3 for static buf indices. R10 CHAMPION.
// LDS: A[3 buf][128 row][32 k] @ 0 + B[3 buf][128 n'][32 k] @ 12288 shorts.
__global__ __launch_bounds__(256, 3) void conv_kernel(
    const unsigned short* __restrict__ xp,
    const unsigned short* __restrict__ w2,
    float* __restrict__ out) {
  __shared__ unsigned short lds[24576];  // 48 KiB

  const int tid = threadIdx.x;
  const int lane = tid & 63;
  const int wv = tid >> 6;  // 0..3
  const int wr = wv >> 1;   // M half (64 rows)
  const int wc = wv & 1;    // N half (64 n')

  const int bid = blockIdx.x;
  const int wg = (bid & 7) * 2048 + (bid >> 3);  // XCD swizzle (16384 % 8 == 0)
  const int mblk = wg >> 3;  // 0..2047
  const int nblk = wg & 7;   // 0..7
  const int b = mblk >> 7;
  const int y = mblk & 127;

  // staging decode: thread t covers row r0 (0..63), lds slot s0 (16B, 4/row)
  const int r0 = tid >> 2;
  const int s0 = tid & 3;
  const int g0 = s0 ^ ((r0 >> 1) & 3);  // inverse swizzle on global source

  const unsigned short* xpt =
      xp + (size_t)(b * 130 + y) * 130 * 128 + r0 * 128 + g0 * 8;
  const unsigned short* wpt =
      w2 + (size_t)nblk * 128 * 1152 + (size_t)r0 * 1152 + g0 * 8;

  const int l15 = lane & 15;
  const int lhi = lane >> 4;
  const int sa = (lhi ^ ((l15 >> 1) & 3)) * 8;  // read-side swizzled slot
  const int aRd = wr * 2048 + l15 * 32 + sa;            // + p*4096
  const int bRd = 12288 + wc * 2048 + l15 * 32 + sa;    // + p*4096

  f32x4 acc[4][4];
#pragma unroll
  for (int mf = 0; mf < 4; ++mf)
#pragma unroll
    for (int nf = 0; nf < 4; ++nf) acc[mf][nf] = (f32x4){0.f, 0.f, 0.f, 0.f};

  // stage K-tile T (tap=T>>2, chq=T&3) into buf P: 4 gloads (A hf0/1, B hf0/1)
#define STAGE_T(P, T)                                                         \
  {                                                                           \
    const int tp_ = (T) >> 2, cq_ = (T) & 3;                                  \
    const int dy_ = tp_ / 3, dx_ = tp_ - dy_ * 3;                             \
    _Pragma("unroll") for (int hf_ = 0; hf_ < 2; ++hf_) {                     \
      gload16(xpt + ((size_t)dy_ * 130 + hf_ * 64 + dx_) * 128 + cq_ * 32,    \
              lds + (P) * 4096 + hf_ * 2048 + wv * 512);                      \
      gload16(wpt + (size_t)hf_ * 64 * 1152 + tp_ * 128 + cq_ * 32,           \
              lds + 12288 + (P) * 4096 + hf_ * 2048 + wv * 512);              \
    }                                                                         \
  }

#define VMW4 asm volatile("s_waitcnt vmcnt(4)" ::: "memory")
#define VMW0 asm volatile("s_waitcnt vmcnt(0)" ::: "memory")
#define SCH0 __builtin_amdgcn_sched_barrier(0)

  // tile T from buf P; stage T+2 into PN2
#define BODY(P, PN2, T)                                                       \
  {                                                                           \
    if ((T) + 2 < 36) STAGE_T(PN2, (T) + 2);                                  \
    const unsigned short* pA_ = lds + (P) * 4096 + aRd;                       \
    const unsigned short* pB_ = lds + (P) * 4096 + bRd;                       \
    short8 af[4], bf[4];                                                      \
    _Pragma("unroll") for (int q = 0; q < 4; ++q)                             \
        af[q] = *(const short8*)(pA_ + q * 512);                              \
    _Pragma("unroll") for (int n = 0; n < 4; ++n)                             \
        bf[n] = *(const short8*)(pB_ + n * 512);                              \
    __builtin_amdgcn_s_setprio(1);                                            \
    _Pragma("unroll") for (int q = 0; q < 4; ++q)                             \
        _Pragma("unroll") for (int n = 0; n < 4; ++n)                         \
            acc[q][n] = __builtin_amdgcn_mfma_f32_16x16x32_bf16(              \
                af[q], bf[n], acc[q][n], 0, 0, 0);                            \
    __builtin_amdgcn_s_setprio(0);                                            \
    SCH0;                                                                     \
    if ((T) < 34) { VMW4; } else { VMW0; }                                    \
    __builtin_amdgcn_s_barrier();                                             \
  }

  // ---- prologue: stage t0 -> buf0, t1 -> buf1; force t0; barrier
  STAGE_T(0, 0);
  STAGE_T(1, 1);
  VMW4;
  SCH0;
  __builtin_amdgcn_s_barrier();

#pragma unroll 1
  for (int j = 0; j < 12; ++j) {
    const int t0 = j * 3;
    BODY(0, 2, t0);
    BODY(1, 0, t0 + 1);
    BODY(2, 1, t0 + 2);
  }

#undef BODY
#undef STAGE_T
#undef VMW4
#undef VMW0
#undef SCH0

  // ---- epilogue: max over 8 rotations (8 adjacent n' cols), coalesced store
  float* lE = (float*)lds;  // [128 pix][17] fp32
#pragma unroll
  for (int mf = 0; mf < 4; ++mf)
#pragma unroll
    for (int nf = 0; nf < 4; ++nf)
#pragma unroll
      for (int j = 0; j < 4; ++j) {
        float v = acc[mf][nf][j];
        v = fmaxf(v, __shfl_xor(v, 1, 64));
        v = fmaxf(v, __shfl_xor(v, 2, 64));
        v = fmaxf(v, __shfl_xor(v, 4, 64));
        if ((lane & 7) == 0) {
          int pix = wr * 64 + mf * 16 + lhi * 4 + j;
          int ol = wc * 8 + nf * 2 + ((lane >> 3) & 1);
          lE[pix * 17 + ol] = v;
        }
      }
  __syncthreads();
  const size_t obase = ((size_t)(b * 128 + nblk * 16) * 128 + y) * 128;
#pragma unroll
  for (int i = 0; i < 8; ++i) {
    int idx = i * 256 + tid;
    int ol = idx >> 7;   // 0..15
    int xx = idx & 127;
    out[obase + (size_t)ol * 16384 + xx] = lE[xx * 17 + ol];
  }
}

extern "C" void kernel_launch(void* const* d_in, const int* in_sizes, int n_in,
                              void* d_out, int out_size, void* d_ws, size_t ws_size,
                              hipStream_t stream) {
  const float* x = (const float*)d_in[0];
  const float* w = (const float*)d_in[1];
  const float* ra = (const float*)d_in[2];
  float* out = (float*)d_out;
  unsigned short* xp = (unsigned short*)d_ws;
  unsigned short* w2 = (unsigned short*)((char*)d_ws + XP_BYTES);

  hipLaunchKernelGGL(wprep_kernel, dim3(512), dim3(256), 0, stream, w, ra, w2);
  hipLaunchKernelGGL(xprep_kernel, dim3(130, 16), dim3(256), 0, stream, x, xp);
  hipLaunchKernelGGL(conv_kernel, dim3(16384), dim3(256), 0, stream, xp, w2, out);
}